// Round 12
// baseline (892.828 us; speedup 1.0000x reference)
//
#include <hip/hip_runtime.h>

#define T_STEPS 100
#define B_SIZE  512
#define H_SIZE  512
#define I_SIZE  700
#define O_SIZE  20

#define ALPHA 0.8187307530779818f   // exp(-0.001/0.005) rounded to f32
#define BETA  0.9048374180359595f   // exp(-0.001/0.010) rounded to f32
#define REG   1e-7

#define RES_ADD(ii, ww)                                              \
    switch ((ii) & 3) {                                              \
        case 0:  e0 = __fadd_rn(e0, (ww)); break;                    \
        case 1:  e1 = __fadd_rn(e1, (ww)); break;                    \
        case 2:  e2 = __fadd_rn(e2, (ww)); break;                    \
        default: e3 = __fadd_rn(e3, (ww)); break;                    \
    }

// ---- continue one ascending chain from k to n (4-batched) ----
__device__ __forceinline__ float chain_cont(const int* __restrict__ lst, int k, int n,
                                            const char* __restrict__ Wb, int tid4,
                                            float a) {
    for (; k + 4 <= n; k += 4) {
        int4 q = *(const int4*)&lst[k];
        float w0 = *(const float*)(Wb + (unsigned)(q.x + tid4));
        float w1 = *(const float*)(Wb + (unsigned)(q.y + tid4));
        float w2 = *(const float*)(Wb + (unsigned)(q.z + tid4));
        float w3 = *(const float*)(Wb + (unsigned)(q.w + tid4));
        a = __fadd_rn(a, w0); a = __fadd_rn(a, w1);
        a = __fadd_rn(a, w2); a = __fadd_rn(a, w3);
    }
    for (; k < n; ++k) {
        float w = *(const float*)(Wb + (unsigned)(lst[k] + tid4));
        a = __fadd_rn(a, w);
    }
    return a;
}

// ---------------- transpose: out[c*R + r] = in[r*C + c] ----------------
__global__ void transpose_kernel(const float* __restrict__ in,
                                 float* __restrict__ out, int R, int C) {
    int idx = blockIdx.x * blockDim.x + threadIdx.x;
    if (idx < R * C) {
        int r = idx / C, c = idx % C;
        out[c * R + r] = in[r * C + c];
    }
}

__global__ void init_counts_kernel(int* __restrict__ g) {
    int tid = threadIdx.x;
    if (tid < 2 * H_SIZE) g[tid] = 0;
}

// ---------------- main SNN kernel: one block per batch element ----------------
// Bitwise-identical arithmetic to the verified R7-R11 engine model:
//   einsum dots (cur0, h2): mod-4 residue chains ascending, (L0+L1)+(L2+L3);
//   BLAS dots (cur1): ascending sequential chains, two results added f32;
//   states/filter: rn mul-then-add in reference order.
// Perf: INTERLEAVED independent fadd chains (4-wide einsum quad, 2-wide
// a1/ar pair) to cover FP-add latency; byte-offset lists + VGPR voffset
// addressing; int4 batching; deferred parallel readout.
__global__ __launch_bounds__(512, 1)
void snn_sparse4_kernel(const float* __restrict__ spikes,   // (B,T,I)
                        const float* __restrict__ W0T,      // (I,H)
                        const float* __restrict__ W1T,      // (H,H)
                        const float* __restrict__ WrecT,    // (H,H)
                        const float* __restrict__ WoutT,    // (H,O)
                        const float* __restrict__ bout,     // (O)
                        float* __restrict__ out,            // (B,T+1,O)
                        int* __restrict__ gcnt0,            // (H)
                        int* __restrict__ gcnt1)            // (H)
{
    const int tid  = threadIdx.x;          // h index, 0..511
    const int b    = blockIdx.x;
    const int lane = tid & 63;
    const int wave = tid >> 6;             // 0..7
    const int res  = tid & 3;              // == lane & 3
    const int tid4 = tid << 2;
    const unsigned long long lt = (1ULL << lane) - 1ULL;
    const unsigned long long RM = 0x1111111111111111ULL << res;  // own-residue lanes

    __shared__ __align__(16) int listIn[4][176];   // einsum inputs by residue
    __shared__ __align__(16) int l0Idx[H_SIZE];
    __shared__ __align__(16) int l1A[H_SIZE];
    __shared__ __align__(16) int l1B[H_SIZE];
    __shared__ __align__(16) int cntA[8][4];       // [wave][res]
    __shared__ __align__(16) int cntB[4][4];       // waves 0..2 used
    __shared__ int cnt0[8], cnt1[8];
    __shared__ unsigned long long maskT[T_STEPS][8];
    __shared__ float h2buf[T_STEPS][O_SIZE];

    float m0 = 0.f, s0 = 0.f, m1 = 0.f, s1 = 0.f;
    int   c0 = 0, c1 = 0;

    int* l1Prev = l1A;
    int* l1Cur  = l1B;
    int  n1Prev = 0;

    const char* W0b = (const char*)W0T;
    const char* W1b = (const char*)W1T;
    const char* Wrb = (const char*)WrecT;

    const float* srow = spikes + (size_t)b * T_STEPS * I_SIZE;

    float spA = srow[tid];
    float spB = (tid < I_SIZE - H_SIZE) ? srow[H_SIZE + tid] : 0.f;

    for (int t = 0; t < T_STEPS; ++t) {
        int fA = (spA != 0.f);
        int fB = (spB != 0.f);
        int f0 = ((m0 - 1.0f) > 0.0f);
        int f1 = ((m1 - 1.0f) > 0.0f);

        unsigned long long bA = __ballot(fA);
        unsigned long long bB = __ballot(fB);
        unsigned long long b0 = __ballot(f0);
        unsigned long long b1 = __ballot(f1);
        if (lane == 0) {
            const unsigned long long R0 = 0x1111111111111111ULL;
            cntA[wave][0] = __popcll(bA & R0);
            cntA[wave][1] = __popcll(bA & (R0 << 1));
            cntA[wave][2] = __popcll(bA & (R0 << 2));
            cntA[wave][3] = __popcll(bA & (R0 << 3));
            if (wave < 3) {
                cntB[wave][0] = __popcll(bB & R0);
                cntB[wave][1] = __popcll(bB & (R0 << 1));
                cntB[wave][2] = __popcll(bB & (R0 << 2));
                cntB[wave][3] = __popcll(bB & (R0 << 3));
            }
            cnt0[wave] = __popcll(b0);
            cnt1[wave] = __popcll(b1);
            maskT[t][wave] = b1;
        }
        __syncthreads();                                   // sync 1

        // ---- per-thread prefix: totals for all residues, offsets for own ----
        int nA0=0,nA1=0,nA2=0,nA3=0, oA_mine=0;
        #pragma unroll
        for (int w = 0; w < 8; ++w) {
            int4 c = *(const int4*)cntA[w];
            if (w == wave)
                oA_mine = (res == 0) ? nA0 : (res == 1) ? nA1 : (res == 2) ? nA2 : nA3;
            nA0 += c.x; nA1 += c.y; nA2 += c.z; nA3 += c.w;
        }
        int nB0=0,nB1=0,nB2=0,nB3=0, oB_mine=0;
        #pragma unroll
        for (int w = 0; w < 3; ++w) {
            int4 c = *(const int4*)cntB[w];
            if (w == wave)
                oB_mine = (res == 0) ? nB0 : (res == 1) ? nB1 : (res == 2) ? nB2 : nB3;
            nB0 += c.x; nB1 += c.y; nB2 += c.z; nB3 += c.w;
        }
        int n0 = 0, o0 = 0, n1Cur = 0, o1 = 0;
        #pragma unroll
        for (int w = 0; w < 8; ++w) {
            if (w == wave) { o0 = n0; o1 = n1Cur; }
            n0 += cnt0[w]; n1Cur += cnt1[w];
        }
        const int nR0 = nA0 + nB0, nR1 = nA1 + nB1, nR2 = nA2 + nB2, nR3 = nA3 + nB3;
        const int nA_mine = (res == 0) ? nA0 : (res == 1) ? nA1 : (res == 2) ? nA2 : nA3;

        // ---- order-preserving scatter of byte offsets (ascending per list) ----
        if (fA) listIn[res][oA_mine + __popcll(bA & RM & lt)] = tid << 11;
        if (fB) listIn[res][nA_mine + oB_mine + __popcll(bB & RM & lt)] = (H_SIZE + tid) << 11;
        if (f0) l0Idx[o0 + __popcll(b0 & lt)] = tid << 11;
        if (f1) l1Cur[o1 + __popcll(b1 & lt)] = tid << 11;
        __syncthreads();                                   // sync 2

        // prefetch next step's spikes
        if (t + 1 < T_STEPS) {
            spA = srow[(t + 1) * I_SIZE + tid];
            spB = (tid < I_SIZE - H_SIZE) ? srow[(t + 1) * I_SIZE + H_SIZE + tid] : 0.f;
        }

        // ---- cur0 (einsum semantics): 4 residue chains INTERLEAVED ----
        float e0 = 0.f, e1 = 0.f, e2 = 0.f, e3 = 0.f;
        {
            int m01 = nR0 < nR1 ? nR0 : nR1;
            int m23 = nR2 < nR3 ? nR2 : nR3;
            int mm  = m01 < m23 ? m01 : m23;
            int k = 0;
            for (; k + 4 <= mm; k += 4) {
                int4 q0 = *(const int4*)&listIn[0][k];
                int4 q1 = *(const int4*)&listIn[1][k];
                int4 q2 = *(const int4*)&listIn[2][k];
                int4 q3 = *(const int4*)&listIn[3][k];
                float w00 = *(const float*)(W0b + (unsigned)(q0.x + tid4));
                float w10 = *(const float*)(W0b + (unsigned)(q1.x + tid4));
                float w20 = *(const float*)(W0b + (unsigned)(q2.x + tid4));
                float w30 = *(const float*)(W0b + (unsigned)(q3.x + tid4));
                float w01 = *(const float*)(W0b + (unsigned)(q0.y + tid4));
                float w11 = *(const float*)(W0b + (unsigned)(q1.y + tid4));
                float w21 = *(const float*)(W0b + (unsigned)(q2.y + tid4));
                float w31 = *(const float*)(W0b + (unsigned)(q3.y + tid4));
                float w02 = *(const float*)(W0b + (unsigned)(q0.z + tid4));
                float w12 = *(const float*)(W0b + (unsigned)(q1.z + tid4));
                float w22 = *(const float*)(W0b + (unsigned)(q2.z + tid4));
                float w32 = *(const float*)(W0b + (unsigned)(q3.z + tid4));
                float w03 = *(const float*)(W0b + (unsigned)(q0.w + tid4));
                float w13 = *(const float*)(W0b + (unsigned)(q1.w + tid4));
                float w23 = *(const float*)(W0b + (unsigned)(q2.w + tid4));
                float w33 = *(const float*)(W0b + (unsigned)(q3.w + tid4));
                e0 = __fadd_rn(e0, w00); e1 = __fadd_rn(e1, w10);
                e2 = __fadd_rn(e2, w20); e3 = __fadd_rn(e3, w30);
                e0 = __fadd_rn(e0, w01); e1 = __fadd_rn(e1, w11);
                e2 = __fadd_rn(e2, w21); e3 = __fadd_rn(e3, w31);
                e0 = __fadd_rn(e0, w02); e1 = __fadd_rn(e1, w12);
                e2 = __fadd_rn(e2, w22); e3 = __fadd_rn(e3, w32);
                e0 = __fadd_rn(e0, w03); e1 = __fadd_rn(e1, w13);
                e2 = __fadd_rn(e2, w23); e3 = __fadd_rn(e3, w33);
            }
            e0 = chain_cont(listIn[0], k, nR0, W0b, tid4, e0);
            e1 = chain_cont(listIn[1], k, nR1, W0b, tid4, e1);
            e2 = chain_cont(listIn[2], k, nR2, W0b, tid4, e2);
            e3 = chain_cont(listIn[3], k, nR3, W0b, tid4, e3);
        }
        float cur0 = __fadd_rn(__fadd_rn(e0, e1), __fadd_rn(e2, e3));

        // ---- cur1 (BLAS semantics): a1 and ar chains INTERLEAVED ----
        float a1 = 0.f, ar = 0.f;
        {
            int nmin = n0 < n1Prev ? n0 : n1Prev;
            int k = 0;
            for (; k + 4 <= nmin; k += 4) {
                int4 qa = *(const int4*)&l0Idx[k];
                int4 qb = *(const int4*)&l1Prev[k];
                float wa0 = *(const float*)(W1b + (unsigned)(qa.x + tid4));
                float wb0 = *(const float*)(Wrb + (unsigned)(qb.x + tid4));
                float wa1 = *(const float*)(W1b + (unsigned)(qa.y + tid4));
                float wb1 = *(const float*)(Wrb + (unsigned)(qb.y + tid4));
                float wa2 = *(const float*)(W1b + (unsigned)(qa.z + tid4));
                float wb2 = *(const float*)(Wrb + (unsigned)(qb.z + tid4));
                float wa3 = *(const float*)(W1b + (unsigned)(qa.w + tid4));
                float wb3 = *(const float*)(Wrb + (unsigned)(qb.w + tid4));
                a1 = __fadd_rn(a1, wa0); ar = __fadd_rn(ar, wb0);
                a1 = __fadd_rn(a1, wa1); ar = __fadd_rn(ar, wb1);
                a1 = __fadd_rn(a1, wa2); ar = __fadd_rn(ar, wb2);
                a1 = __fadd_rn(a1, wa3); ar = __fadd_rn(ar, wb3);
            }
            a1 = chain_cont(l0Idx, k, n0, W1b, tid4, a1);
            ar = chain_cont(l1Prev, k, n1Prev, Wrb, tid4, ar);
        }
        float cur1 = __fadd_rn(a1, ar);

        // ---- LIF updates: rn mul-then-add, reference order ----
        float ns0 = __fadd_rn(__fmul_rn(ALPHA, s0), cur0);
        float nm0 = __fmul_rn(__fadd_rn(__fmul_rn(BETA, m0), s0), 1.0f - (float)f0);
        float ns1 = __fadd_rn(__fmul_rn(ALPHA, s1), cur1);
        float nm1 = __fmul_rn(__fadd_rn(__fmul_rn(BETA, m1), s1), 1.0f - (float)f1);
        s0 = ns0; m0 = nm0; s1 = ns1; m1 = nm1;
        c0 += f0; c1 += f1;

        int* tmp = l1Prev; l1Prev = l1Cur; l1Cur = tmp;
        n1Prev = n1Cur;
    }

    atomicAdd(&gcnt0[tid], c0);
    atomicAdd(&gcnt1[tid], c1);
    __syncthreads();   // all maskT writes complete

    // ---- phase 2: h2[t][o] in parallel (einsum semantics, ascending bits) ----
    {
        int grp = tid / O_SIZE;        // 0..25 (threads 500..511 idle)
        int o   = tid % O_SIZE;
        if (grp < 25) {
            for (int tt = grp; tt < T_STEPS; tt += 25) {
                float e0 = 0.f, e1 = 0.f, e2 = 0.f, e3 = 0.f;
                #pragma unroll
                for (int j = 0; j < 8; ++j) {
                    unsigned long long m = maskT[tt][j];
                    int base = j * 64;
                    while (m) {
                        int idx = base + (int)__builtin_ctzll(m);
                        m &= m - 1;
                        float wv = WoutT[(size_t)idx * O_SIZE + o];
                        RES_ADD(idx, wv);
                    }
                }
                h2buf[tt][o] = __fadd_rn(__fadd_rn(e0, e1), __fadd_rn(e2, e3));
            }
        }
    }
    __syncthreads();

    // ---- phase 3: double-exp filter recurrence (20 threads) ----
    if (tid < O_SIZE) {
        float bo  = bout[tid];
        float flt = 0.f, outv = 0.f;
        out[((size_t)b * (T_STEPS + 1)) * O_SIZE + tid] = bo;   // t = 0 row
        for (int tt = 0; tt < T_STEPS; ++tt) {
            float h2   = h2buf[tt][tid];
            float nflt = __fadd_rn(__fmul_rn(ALPHA, flt), h2);
            float nout = __fadd_rn(__fmul_rn(BETA, outv), flt);  // OLD flt
            flt = nflt; outv = nout;
            out[((size_t)b * (T_STEPS + 1) + (tt + 1)) * O_SIZE + tid] = __fadd_rn(nout, bo);
        }
    }
}

// ---------------- reg loss ----------------
__global__ void reg_kernel(const int* __restrict__ g0,
                           const int* __restrict__ g1,
                           float* __restrict__ out_reg) {
    int tid = threadIdx.x;     // 512 threads
    double v0 = (double)g0[tid], v1 = (double)g1[tid];
    double tot = v0 + v1;
    double sq  = v0 * v0 + v1 * v1;
    for (int off = 32; off; off >>= 1) {
        tot += __shfl_down(tot, off, 64);
        sq  += __shfl_down(sq,  off, 64);
    }
    __shared__ double stot[8], ssq[8];
    if ((tid & 63) == 0) { stot[tid >> 6] = tot; ssq[tid >> 6] = sq; }
    __syncthreads();
    if (tid == 0) {
        double Tt = 0.0, Sq = 0.0;
        for (int w = 0; w < 8; ++w) { Tt += stot[w]; Sq += ssq[w]; }
        double reg = REG * (Tt / 26214400.0 + Sq / 512.0);
        *out_reg = (float)reg;
    }
}

extern "C" void kernel_launch(void* const* d_in, const int* in_sizes, int n_in,
                              void* d_out, int out_size, void* d_ws, size_t ws_size,
                              hipStream_t stream) {
    const float* spikes = (const float*)d_in[0];   // (512,100,700)
    const float* W0     = (const float*)d_in[1];   // (512,700)
    const float* W1     = (const float*)d_in[2];   // (512,512)
    const float* Wrec   = (const float*)d_in[3];   // (512,512)
    const float* Wout   = (const float*)d_in[4];   // (20,512)
    const float* bout   = (const float*)d_in[5];   // (20,)
    float* out = (float*)d_out;

    float* W0T   = (float*)d_ws;                       // 700*512 f32
    float* W1T   = W0T   + (size_t)I_SIZE * H_SIZE;    // 512*512
    float* WrecT = W1T   + (size_t)H_SIZE * H_SIZE;    // 512*512
    float* WoutT = WrecT + (size_t)H_SIZE * H_SIZE;    // 512*20
    int*   gcnt0 = (int*)(WoutT + (size_t)H_SIZE * O_SIZE);
    int*   gcnt1 = gcnt0 + H_SIZE;

    int n;
    n = H_SIZE * I_SIZE;
    transpose_kernel<<<(n + 255) / 256, 256, 0, stream>>>(W0, W0T, H_SIZE, I_SIZE);
    n = H_SIZE * H_SIZE;
    transpose_kernel<<<(n + 255) / 256, 256, 0, stream>>>(W1, W1T, H_SIZE, H_SIZE);
    transpose_kernel<<<(n + 255) / 256, 256, 0, stream>>>(Wrec, WrecT, H_SIZE, H_SIZE);
    n = O_SIZE * H_SIZE;
    transpose_kernel<<<(n + 255) / 256, 256, 0, stream>>>(Wout, WoutT, O_SIZE, H_SIZE);

    init_counts_kernel<<<1, 1024, 0, stream>>>(gcnt0);

    snn_sparse4_kernel<<<B_SIZE, H_SIZE, 0, stream>>>(spikes, W0T, W1T, WrecT, WoutT,
                                                      bout, out, gcnt0, gcnt1);

    reg_kernel<<<1, H_SIZE, 0, stream>>>(gcnt0, gcnt1,
                                         out + (size_t)B_SIZE * (T_STEPS + 1) * O_SIZE);
}